// Round 3
// baseline (276.213 us; speedup 1.0000x reference)
//
#include <hip/hip_runtime.h>
#include <hip/hip_bf16.h>
#include <stdint.h>

#define TTOK 1024
#define CDIM 1024
#define NEXP 8
#define IDIM 1024
#define TWOI 2048
#define NSLOT 2048

typedef float f32x4 __attribute__((ext_vector_type(4)));
typedef short s16x8 __attribute__((ext_vector_type(8)));
typedef unsigned short u16;
typedef u16 u16x4 __attribute__((ext_vector_type(4)));
typedef u16 u16x8 __attribute__((ext_vector_type(8)));

__device__ __forceinline__ u16 f2bf(float f) {
  unsigned x = __float_as_uint(f);
  x += 0x7fffu + ((x >> 16) & 1u);
  return (u16)(x >> 16);
}

__device__ __forceinline__ void gload_lds16(const void* g, void* l) {
  __builtin_amdgcn_global_load_lds(
      (const __attribute__((address_space(1))) void*)g,
      (__attribute__((address_space(3))) void*)l, 16, 0, 0);
}

// ---------------- router: logits -> softmax -> top2 ----------------
__global__ __launch_bounds__(64) void router_k(const float* __restrict__ x,
                                               const float* __restrict__ rw,
                                               int* __restrict__ meta,
                                               float* __restrict__ topw,
                                               int* __restrict__ topidx) {
  const int t = blockIdx.x;
  const int lane = threadIdx.x;
  float p[NEXP];
#pragma unroll
  for (int e = 0; e < NEXP; ++e) p[e] = 0.f;
  const float* xr = x + (size_t)t * CDIM;
  for (int c0 = lane * 4; c0 < CDIM; c0 += 64 * 4) {
    f32x4 xv = *(const f32x4*)(xr + c0);
#pragma unroll
    for (int e = 0; e < NEXP; ++e) {
      f32x4 wv = *(const f32x4*)(rw + (size_t)e * CDIM + c0);
      p[e] += xv[0] * wv[0] + xv[1] * wv[1] + xv[2] * wv[2] + xv[3] * wv[3];
    }
  }
#pragma unroll
  for (int e = 0; e < NEXP; ++e) {
    float v = p[e];
#pragma unroll
    for (int off = 32; off >= 1; off >>= 1) v += __shfl_xor(v, off);
    p[e] = v;
  }
  if (lane == 0) {
    float m = p[0];
#pragma unroll
    for (int e = 1; e < NEXP; ++e) m = fmaxf(m, p[e]);
    float pe[NEXP];
    float den = 0.f;
#pragma unroll
    for (int e = 0; e < NEXP; ++e) { pe[e] = __expf(p[e] - m); den += pe[e]; }
    int i0 = 0;
#pragma unroll
    for (int e = 1; e < NEXP; ++e) if (p[e] > p[i0]) i0 = e;
    int i1 = (i0 == 0) ? 1 : 0;
#pragma unroll
    for (int e = 0; e < NEXP; ++e) if (e != i0 && p[e] > p[i1]) i1 = e;
    const float inv = 1.f / den;
    topw[t * 2] = pe[i0] * inv;
    topw[t * 2 + 1] = pe[i1] * inv;
    topidx[t * 2] = i0;
    topidx[t * 2 + 1] = i1;
    atomicAdd(&meta[i0], 1);
    atomicAdd(&meta[i1], 1);
  }
}

// ---------------- offsets (prefix over 8 experts) ----------------
__global__ void offsets_k(int* __restrict__ meta) {
  if (threadIdx.x == 0 && blockIdx.x == 0) {
    int acc = 0;
    for (int e = 0; e < NEXP; ++e) { meta[16 + e] = acc; acc += meta[e]; }
    meta[16 + NEXP] = acc;
  }
}

// ---------------- build token lists ----------------
__global__ __launch_bounds__(256) void build_k(const int* __restrict__ topidx,
                                               int* __restrict__ meta,
                                               int* __restrict__ slot_token,
                                               int* __restrict__ slot_expert,
                                               int* __restrict__ tok2slot) {
  const int t = blockIdx.x * 256 + threadIdx.x;
  if (t >= TTOK) return;
#pragma unroll
  for (int k = 0; k < 2; ++k) {
    const int e = topidx[t * 2 + k];
    const int pos = atomicAdd(&meta[8 + e], 1);
    const int s = meta[16 + e] + pos;
    slot_token[s] = t;
    slot_expert[s] = e;
    tok2slot[t * 2 + k] = s;
  }
}

// ---------------- cast x to bf16 (8 elems/thread) ----------------
__global__ __launch_bounds__(256) void castx_k(const float* __restrict__ x,
                                               u16* __restrict__ xb) {
  const int i = (blockIdx.x * 256 + threadIdx.x) * 8;
  f32x4 v0 = *(const f32x4*)(x + i);
  f32x4 v1 = *(const f32x4*)(x + i + 4);
  u16x8 o;
#pragma unroll
  for (int q = 0; q < 4; ++q) o[q] = f2bf(v0[q]);
#pragma unroll
  for (int q = 0; q < 4; ++q) o[4 + q] = f2bf(v1[q]);
  *(u16x8*)(xb + i) = o;
}

// ---------------- grouped GEMM: O[slot, n] = sum_k A[row(slot), k] * W[e, n, k] ----------------
// A bf16 [*, K]; W fp32 [E, N, K] (B^T layout); O fp32 [NSLOT, N].
template <bool GATHER, bool BIAS>
__global__ __launch_bounds__(256) void gemm_k(const u16* __restrict__ A,
                                              const float* __restrict__ W,
                                              float* __restrict__ O,
                                              const float* __restrict__ bias,
                                              const int* __restrict__ meta,
                                              const int* __restrict__ slot_token,
                                              int N, int K) {
  const int e = blockIdx.z;
  const int cnt = meta[e];
  const int m0 = blockIdx.y * 128;
  if (m0 >= cnt) return;
  const int off = meta[16 + e];
  const int n0 = blockIdx.x * 128;

  __shared__ u16 sA[128 * 64];
  __shared__ u16 sB[128 * 64];

  const int tid = threadIdx.x;
  const int lane = tid & 63;
  const int w = tid >> 6;
  const int wr = w >> 1;
  const int wc = w & 1;

  // A staging: 4 global_load_lds(16B) per wave per K-step.
  // LDS linear fill: lane writes bytes [base + lane*16); row = (w*4+i)*8 + lane>>3, chunk = lane&7.
  // Source pre-swizzled so LDS[r][c] holds global chunk c^(r&7)  (rule #21).
  const u16* aSrc[4];
#pragma unroll
  for (int i = 0; i < 4; ++i) {
    const int r = (w * 4 + i) * 8 + (lane >> 3);
    int rr = m0 + r;
    if (rr > cnt - 1) rr = cnt - 1;  // clamp padded rows to a valid address
    const int rowg = GATHER ? slot_token[off + rr] : (off + rr);
    const int cs = (lane & 7) ^ (r & 7);
    aSrc[i] = A + (size_t)rowg * K + cs * 8;
  }

  // B staging: thread covers row tid>>1, half tid&1 (32 of 64 k); fp32->bf16 convert.
  const int brow = tid >> 1;
  const int bhalf = tid & 1;
  const float* bSrc = W + ((size_t)e * N + (n0 + brow)) * K + bhalf * 32;
  u16* sBrow = sB + brow * 64;
  const int brow7 = brow & 7;

  f32x4 acc[4][4];
#pragma unroll
  for (int m = 0; m < 4; ++m)
#pragma unroll
    for (int n = 0; n < 4; ++n) acc[m][n] = (f32x4){0.f, 0.f, 0.f, 0.f};

  for (int k0 = 0; k0 < K; k0 += 64) {
#pragma unroll
    for (int i = 0; i < 4; ++i)
      gload_lds16(aSrc[i] + k0, sA + (w * 4 + i) * 512);

    const float* bs = bSrc + k0;
#pragma unroll
    for (int cc = 0; cc < 4; ++cc) {
      f32x4 v0 = *(const f32x4*)(bs + cc * 8);
      f32x4 v1 = *(const f32x4*)(bs + cc * 8 + 4);
      u16x8 pk;
#pragma unroll
      for (int q = 0; q < 4; ++q) pk[q] = f2bf(v0[q]);
#pragma unroll
      for (int q = 0; q < 4; ++q) pk[4 + q] = f2bf(v1[q]);
      const int chunk = bhalf * 4 + cc;
      *(u16x8*)(sBrow + ((chunk ^ brow7) * 8)) = pk;
    }
    __syncthreads();

#pragma unroll
    for (int kh = 0; kh < 2; ++kh) {
      const int j = kh * 4 + (lane >> 4);
      s16x8 af[4], bf[4];
#pragma unroll
      for (int m = 0; m < 4; ++m) {
        const int r = wr * 64 + m * 16 + (lane & 15);
        af[m] = *(const s16x8*)(sA + r * 64 + ((j ^ (r & 7)) * 8));
      }
#pragma unroll
      for (int n = 0; n < 4; ++n) {
        const int r = wc * 64 + n * 16 + (lane & 15);
        bf[n] = *(const s16x8*)(sB + r * 64 + ((j ^ (r & 7)) * 8));
      }
#pragma unroll
      for (int m = 0; m < 4; ++m)
#pragma unroll
        for (int n = 0; n < 4; ++n)
          acc[m][n] = __builtin_amdgcn_mfma_f32_16x16x32_bf16(af[m], bf[n], acc[m][n], 0, 0, 0);
    }
    __syncthreads();
  }

  // epilogue: C/D layout col=lane&15, row=(lane>>4)*4+reg
#pragma unroll
  for (int m = 0; m < 4; ++m) {
#pragma unroll
    for (int jj = 0; jj < 4; ++jj) {
      const int tr = wr * 64 + m * 16 + ((lane >> 4) * 4) + jj;
      if (m0 + tr < cnt) {
        const size_t slot = (size_t)(off + m0 + tr);
#pragma unroll
        for (int n = 0; n < 4; ++n) {
          const int col = n0 + wc * 64 + n * 16 + (lane & 15);
          float v = acc[m][n][jj];
          if (BIAS) v += bias[(size_t)e * N + col];
          O[slot * N + col] = v;
        }
      }
    }
  }
}

// ---------------- swiglu: a = silu(g + bg) * (u + bu), bf16 ----------------
__global__ __launch_bounds__(256) void swiglu_k(const float* __restrict__ h,
                                                const float* __restrict__ b_in,
                                                const int* __restrict__ slot_expert,
                                                u16* __restrict__ a) {
  const int s = blockIdx.x;
  const int e = slot_expert[s];
  const int i = threadIdx.x * 4;
  f32x4 g = *(const f32x4*)(h + (size_t)s * TWOI + i);
  f32x4 u = *(const f32x4*)(h + (size_t)s * TWOI + IDIM + i);
  f32x4 bg = *(const f32x4*)(b_in + (size_t)e * TWOI + i);
  f32x4 bu = *(const f32x4*)(b_in + (size_t)e * TWOI + IDIM + i);
  u16x4 o;
#pragma unroll
  for (int q = 0; q < 4; ++q) {
    const float gg = g[q] + bg[q];
    const float uu = u[q] + bu[q];
    const float sv = gg / (1.f + __expf(-gg));
    o[q] = f2bf(sv * uu);
  }
  *(u16x4*)(a + (size_t)s * IDIM + i) = o;
}

// ---------------- combine: out[t] = w0*y[s0] + w1*y[s1] ----------------
__global__ __launch_bounds__(256) void combine_k(const float* __restrict__ y,
                                                 const float* __restrict__ topw,
                                                 const int* __restrict__ tok2slot,
                                                 float* __restrict__ out) {
  const int idx = blockIdx.x * 256 + threadIdx.x;  // over T*C/4
  const int t = idx >> 8;
  const int c4 = (idx & 255) * 4;
  const int s0 = tok2slot[t * 2];
  const int s1 = tok2slot[t * 2 + 1];
  const float w0 = topw[t * 2];
  const float w1 = topw[t * 2 + 1];
  f32x4 y0 = *(const f32x4*)(y + (size_t)s0 * CDIM + c4);
  f32x4 y1 = *(const f32x4*)(y + (size_t)s1 * CDIM + c4);
  f32x4 o;
#pragma unroll
  for (int q = 0; q < 4; ++q) o[q] = w0 * y0[q] + w1 * y1[q];
  *(f32x4*)(out + (size_t)t * CDIM + c4) = o;
}

extern "C" void kernel_launch(void* const* d_in, const int* in_sizes, int n_in,
                              void* d_out, int out_size, void* d_ws, size_t ws_size,
                              hipStream_t stream) {
  const float* x = (const float*)d_in[0];
  const float* rw = (const float*)d_in[1];
  const float* w_in = (const float*)d_in[2];
  const float* b_in = (const float*)d_in[3];
  const float* w_out = (const float*)d_in[4];
  const float* b_out = (const float*)d_in[5];
  float* out = (float*)d_out;
  char* ws = (char*)d_ws;

  // ws layout (bytes)
  int* meta = (int*)ws;                               // [0..25): counts@0, cursors@8, offsets@16
  int* slot_token = (int*)(ws + 1024);                // 2048 ints
  int* slot_expert = (int*)(ws + 1024 + 8192);        // 2048 ints
  int* tok2slot = (int*)(ws + 1024 + 16384);          // 2048 ints
  float* topw = (float*)(ws + 1024 + 24576);          // 2048 f32
  int* topidx = (int*)(ws + 1024 + 32768);            // 2048 ints
  u16* xb = (u16*)(ws + 65536);                       // 1M bf16 = 2MB
  float* h = (float*)(ws + 65536 + (2u << 20));       // 2048*2048 f32 = 16MB
  u16* a = (u16*)(ws + 65536 + (18u << 20));          // 2048*1024 bf16 = 4MB
  float* y = (float*)(ws + 65536 + (22u << 20));      // 2048*1024 f32 = 8MB

  hipMemsetAsync(meta, 0, 128, stream);
  router_k<<<TTOK, 64, 0, stream>>>(x, rw, meta, topw, topidx);
  offsets_k<<<1, 64, 0, stream>>>(meta);
  build_k<<<4, 256, 0, stream>>>(topidx, meta, slot_token, slot_expert, tok2slot);
  castx_k<<<512, 256, 0, stream>>>(x, xb);
  // grid.y = 16: worst-case 2048 rows may land on ONE expert; surplus blocks
  // exit after one scalar load (m0 >= cnt).
  gemm_k<true, false><<<dim3(16, 16, NEXP), 256, 0, stream>>>(
      xb, w_in, h, nullptr, meta, slot_token, TWOI, CDIM);
  swiglu_k<<<NSLOT, 256, 0, stream>>>(h, b_in, slot_expert, a);
  gemm_k<false, true><<<dim3(8, 16, NEXP), 256, 0, stream>>>(
      a, w_out, y, b_out, meta, slot_token, CDIM, IDIM);
  combine_k<<<1024, 256, 0, stream>>>(y, topw, tok2slot, out);
}

// Round 6
// 219.089 us; speedup vs baseline: 1.2607x; 1.2607x over previous
//
#include <hip/hip_runtime.h>
#include <hip/hip_bf16.h>
#include <stdint.h>

#define TTOK 1024
#define CDIM 1024
#define NEXP 8
#define IDIM 1024
#define TWOI 2048
#define NSLOT 2048

typedef float f32x4 __attribute__((ext_vector_type(4)));
typedef short s16x8 __attribute__((ext_vector_type(8)));
typedef unsigned short u16;
typedef u16 u16x4 __attribute__((ext_vector_type(4)));
typedef u16 u16x8 __attribute__((ext_vector_type(8)));

__device__ __forceinline__ u16 f2bf(float f) {
  unsigned x = __float_as_uint(f);
  x += 0x7fffu + ((x >> 16) & 1u);
  return (u16)(x >> 16);
}

__device__ __forceinline__ void gload_lds16(const void* g, void* l) {
  __builtin_amdgcn_global_load_lds(
      (const __attribute__((address_space(1))) void*)g,
      (__attribute__((address_space(3))) void*)l, 16, 0, 0);
}

// ---------------- router: logits -> softmax -> top2; also emits bf16 x ----------------
__global__ __launch_bounds__(64) void router_k(const float* __restrict__ x,
                                               const float* __restrict__ rw,
                                               float* __restrict__ topw,
                                               int* __restrict__ topidx,
                                               u16* __restrict__ xb) {
  const int t = blockIdx.x;
  const int lane = threadIdx.x;
  float p[NEXP];
#pragma unroll
  for (int e = 0; e < NEXP; ++e) p[e] = 0.f;
  const float* xr = x + (size_t)t * CDIM;
  u16* xbr = xb + (size_t)t * CDIM;
  for (int c0 = lane * 4; c0 < CDIM; c0 += 64 * 4) {
    f32x4 xv = *(const f32x4*)(xr + c0);
    u16x4 xc;
#pragma unroll
    for (int q = 0; q < 4; ++q) xc[q] = f2bf(xv[q]);
    *(u16x4*)(xbr + c0) = xc;   // fused fp32->bf16 cast of x
#pragma unroll
    for (int e = 0; e < NEXP; ++e) {
      f32x4 wv = *(const f32x4*)(rw + (size_t)e * CDIM + c0);
      p[e] += xv[0] * wv[0] + xv[1] * wv[1] + xv[2] * wv[2] + xv[3] * wv[3];
    }
  }
#pragma unroll
  for (int e = 0; e < NEXP; ++e) {
    float v = p[e];
#pragma unroll
    for (int off = 32; off >= 1; off >>= 1) v += __shfl_xor(v, off);
    p[e] = v;
  }
  if (lane == 0) {
    float m = p[0];
#pragma unroll
    for (int e = 1; e < NEXP; ++e) m = fmaxf(m, p[e]);
    float pe[NEXP];
    float den = 0.f;
#pragma unroll
    for (int e = 0; e < NEXP; ++e) { pe[e] = __expf(p[e] - m); den += pe[e]; }
    int i0 = 0;
#pragma unroll
    for (int e = 1; e < NEXP; ++e) if (p[e] > p[i0]) i0 = e;
    int i1 = (i0 == 0) ? 1 : 0;
#pragma unroll
    for (int e = 0; e < NEXP; ++e) if (e != i0 && p[e] > p[i1]) i1 = e;
    const float inv = 1.f / den;
    topw[t * 2] = pe[i0] * inv;
    topw[t * 2 + 1] = pe[i1] * inv;
    topidx[t * 2] = i0;
    topidx[t * 2 + 1] = i1;
  }
}

// ---------------- build: histogram + prefix + scatter, one block ----------------
__global__ __launch_bounds__(1024) void build_k(const int* __restrict__ topidx,
                                                int* __restrict__ meta,
                                                int* __restrict__ slot_token,
                                                int* __restrict__ slot_expert,
                                                int* __restrict__ tok2slot) {
  __shared__ int cnt[NEXP], off[NEXP], cur[NEXP];
  const int t = threadIdx.x;
  if (t < NEXP) { cnt[t] = 0; cur[t] = 0; }
  __syncthreads();
  const int e0 = topidx[t * 2];
  const int e1 = topidx[t * 2 + 1];
  atomicAdd(&cnt[e0], 1);
  atomicAdd(&cnt[e1], 1);
  __syncthreads();
  if (t == 0) {
    int acc = 0;
    for (int e = 0; e < NEXP; ++e) { off[e] = acc; acc += cnt[e]; }
  }
  __syncthreads();
  if (t < NEXP) { meta[t] = cnt[t]; meta[16 + t] = off[t]; }
  {
    const int p0 = atomicAdd(&cur[e0], 1);
    const int s0 = off[e0] + p0;
    slot_token[s0] = t;
    slot_expert[s0] = e0;
    tok2slot[t * 2] = s0;
    const int p1 = atomicAdd(&cur[e1], 1);
    const int s1 = off[e1] + p1;
    slot_token[s1] = t;
    slot_expert[s1] = e1;
    tok2slot[t * 2 + 1] = s1;
  }
}

// ---------------- grouped GEMM: O[slot, n] = sum_k A[row(slot), k] * W[e, n, k] ----------------
// A bf16 [*, K]; W fp32 [E, N, K] (B^T layout); O fp32 [NSLOT, N].
// BN must be 64. Waves arranged 2x2; wave tile (BM/2) x 32.
template <int BM, bool GATHER, bool BIAS>
__global__ __launch_bounds__(256) void gemm_k(const u16* __restrict__ A,
                                              const float* __restrict__ W,
                                              float* __restrict__ O,
                                              const float* __restrict__ bias,
                                              const int* __restrict__ meta,
                                              const int* __restrict__ slot_token,
                                              int N, int K) {
  constexpr int BN = 64;
  constexpr int WM = BM / 2;
  constexpr int WN = BN / 2;
  constexpr int MR = WM / 16;
  constexpr int NR = WN / 16;

  const int e = blockIdx.z;
  const int cnt = meta[e];
  const int m0 = blockIdx.y * BM;
  if (m0 >= cnt) return;
  const int off = meta[16 + e];
  const int n0 = blockIdx.x * BN;

  __shared__ u16 sA[BM * 64];
  __shared__ u16 sB[BN * 64];

  const int tid = threadIdx.x;
  const int lane = tid & 63;
  const int w = tid >> 6;
  const int wr = w >> 1;
  const int wc = w & 1;

  // A staging: per wave BM/32 x global_load_lds(16B). Linear LDS dest;
  // source pre-swizzled so LDS[r][c] holds global chunk c^(r&7)  (rule #21).
  const u16* aSrc[BM / 32];
#pragma unroll
  for (int i = 0; i < BM / 32; ++i) {
    const int r = w * (BM / 4) + i * 8 + (lane >> 3);
    int rr = m0 + r;
    if (rr > cnt - 1) rr = cnt - 1;  // clamp padded rows to a valid address
    const int rowg = GATHER ? slot_token[off + rr] : (off + rr);
    const int cs = (lane & 7) ^ (r & 7);
    aSrc[i] = A + (size_t)rowg * K + cs * 8;
  }

  // B staging: thread covers row tid>>2, quarter tid&3 (16 of 64 k); fp32->bf16.
  const int brow = tid >> 2;
  const int bq = tid & 3;
  const float* bSrc = W + ((size_t)e * N + (n0 + brow)) * K + bq * 16;
  u16* sBrow = sB + brow * 64;
  const int brow7 = brow & 7;

  f32x4 acc[MR][NR];
#pragma unroll
  for (int m = 0; m < MR; ++m)
#pragma unroll
    for (int n = 0; n < NR; ++n) acc[m][n] = (f32x4){0.f, 0.f, 0.f, 0.f};

  for (int k0 = 0; k0 < K; k0 += 64) {
#pragma unroll
    for (int i = 0; i < BM / 32; ++i)
      gload_lds16(aSrc[i] + k0, sA + (w * (BM / 4) + i * 8) * 64 + lane * 8);

    {
      const float* bs = bSrc + k0;
      f32x4 v0 = *(const f32x4*)(bs);
      f32x4 v1 = *(const f32x4*)(bs + 4);
      f32x4 v2 = *(const f32x4*)(bs + 8);
      f32x4 v3 = *(const f32x4*)(bs + 12);
      u16x8 lo, hi;
#pragma unroll
      for (int q = 0; q < 4; ++q) lo[q] = f2bf(v0[q]);
#pragma unroll
      for (int q = 0; q < 4; ++q) lo[4 + q] = f2bf(v1[q]);
#pragma unroll
      for (int q = 0; q < 4; ++q) hi[q] = f2bf(v2[q]);
#pragma unroll
      for (int q = 0; q < 4; ++q) hi[4 + q] = f2bf(v3[q]);
      *(u16x8*)(sBrow + (((bq * 2) ^ brow7) * 8)) = lo;
      *(u16x8*)(sBrow + (((bq * 2 + 1) ^ brow7) * 8)) = hi;
    }
    __syncthreads();

#pragma unroll
    for (int kh = 0; kh < 2; ++kh) {
      const int j = kh * 4 + (lane >> 4);
      s16x8 af[MR], bf[NR];
#pragma unroll
      for (int m = 0; m < MR; ++m) {
        const int r = wr * WM + m * 16 + (lane & 15);
        af[m] = *(const s16x8*)(sA + r * 64 + ((j ^ (r & 7)) * 8));
      }
#pragma unroll
      for (int n = 0; n < NR; ++n) {
        const int r = wc * WN + n * 16 + (lane & 15);
        bf[n] = *(const s16x8*)(sB + r * 64 + ((j ^ (r & 7)) * 8));
      }
#pragma unroll
      for (int m = 0; m < MR; ++m)
#pragma unroll
        for (int n = 0; n < NR; ++n)
          acc[m][n] = __builtin_amdgcn_mfma_f32_16x16x32_bf16(af[m], bf[n], acc[m][n], 0, 0, 0);
    }
    __syncthreads();
  }

  // epilogue: C/D layout col=lane&15, row=(lane>>4)*4+reg
#pragma unroll
  for (int m = 0; m < MR; ++m) {
#pragma unroll
    for (int jj = 0; jj < 4; ++jj) {
      const int tr = wr * WM + m * 16 + ((lane >> 4) * 4) + jj;
      if (m0 + tr < cnt) {
        const size_t slot = (size_t)(off + m0 + tr);
#pragma unroll
        for (int n = 0; n < NR; ++n) {
          const int col = n0 + wc * WN + n * 16 + (lane & 15);
          float v = acc[m][n][jj];
          if (BIAS) v += bias[(size_t)e * N + col];
          O[slot * N + col] = v;
        }
      }
    }
  }
}

// ---------------- swiglu: a = silu(g + bg) * (u + bu), bf16 ----------------
__global__ __launch_bounds__(256) void swiglu_k(const float* __restrict__ h,
                                                const float* __restrict__ b_in,
                                                const int* __restrict__ slot_expert,
                                                u16* __restrict__ a) {
  const int s = blockIdx.x;
  const int e = slot_expert[s];
  const int i = threadIdx.x * 4;
  f32x4 g = *(const f32x4*)(h + (size_t)s * TWOI + i);
  f32x4 u = *(const f32x4*)(h + (size_t)s * TWOI + IDIM + i);
  f32x4 bg = *(const f32x4*)(b_in + (size_t)e * TWOI + i);
  f32x4 bu = *(const f32x4*)(b_in + (size_t)e * TWOI + IDIM + i);
  u16x4 o;
#pragma unroll
  for (int q = 0; q < 4; ++q) {
    const float gg = g[q] + bg[q];
    const float uu = u[q] + bu[q];
    const float sv = gg / (1.f + __expf(-gg));
    o[q] = f2bf(sv * uu);
  }
  *(u16x4*)(a + (size_t)s * IDIM + i) = o;
}

// ---------------- combine: out[t] = w0*y[s0] + w1*y[s1] ----------------
__global__ __launch_bounds__(256) void combine_k(const float* __restrict__ y,
                                                 const float* __restrict__ topw,
                                                 const int* __restrict__ tok2slot,
                                                 float* __restrict__ out) {
  const int idx = blockIdx.x * 256 + threadIdx.x;  // over T*C/4
  const int t = idx >> 8;
  const int c4 = (idx & 255) * 4;
  const int s0 = tok2slot[t * 2];
  const int s1 = tok2slot[t * 2 + 1];
  const float w0 = topw[t * 2];
  const float w1 = topw[t * 2 + 1];
  f32x4 y0 = *(const f32x4*)(y + (size_t)s0 * CDIM + c4);
  f32x4 y1 = *(const f32x4*)(y + (size_t)s1 * CDIM + c4);
  f32x4 o;
#pragma unroll
  for (int q = 0; q < 4; ++q) o[q] = w0 * y0[q] + w1 * y1[q];
  *(f32x4*)(out + (size_t)t * CDIM + c4) = o;
}

extern "C" void kernel_launch(void* const* d_in, const int* in_sizes, int n_in,
                              void* d_out, int out_size, void* d_ws, size_t ws_size,
                              hipStream_t stream) {
  const float* x = (const float*)d_in[0];
  const float* rw = (const float*)d_in[1];
  const float* w_in = (const float*)d_in[2];
  const float* b_in = (const float*)d_in[3];
  const float* w_out = (const float*)d_in[4];
  const float* b_out = (const float*)d_in[5];
  float* out = (float*)d_out;
  char* ws = (char*)d_ws;

  // ws layout (bytes)
  int* meta = (int*)ws;                               // counts@0, offsets@16
  int* slot_token = (int*)(ws + 1024);                // 2048 ints
  int* slot_expert = (int*)(ws + 1024 + 8192);        // 2048 ints
  int* tok2slot = (int*)(ws + 1024 + 16384);          // 2048 ints
  float* topw = (float*)(ws + 1024 + 24576);          // 2048 f32
  int* topidx = (int*)(ws + 1024 + 32768);            // 2048 ints
  u16* xb = (u16*)(ws + 65536);                       // 1M bf16 = 2MB
  float* h = (float*)(ws + 65536 + (2u << 20));       // 2048*2048 f32 = 16MB
  u16* a = (u16*)(ws + 65536 + (18u << 20));          // 2048*1024 bf16 = 4MB
  float* y = (float*)(ws + 65536 + (22u << 20));      // 2048*1024 f32 = 8MB

  // no memset needed: build_k rewrites every meta field read downstream.
  router_k<<<TTOK, 64, 0, stream>>>(x, rw, topw, topidx, xb);
  build_k<<<1, 1024, 0, stream>>>(topidx, meta, slot_token, slot_expert, tok2slot);
  // GEMM1: BM=128, BN=64 -> 32 n-tiles; ~512 active blocks (2/CU) at cnt~256.
  gemm_k<128, true, false><<<dim3(32, 16, NEXP), 256, 0, stream>>>(
      xb, w_in, h, nullptr, meta, slot_token, TWOI, CDIM);
  swiglu_k<<<NSLOT, 256, 0, stream>>>(h, b_in, slot_expert, a);
  // GEMM2: BM=64, BN=64 -> 16 n-tiles; ~512 active blocks (2/CU) at cnt~256.
  gemm_k<64, false, true><<<dim3(16, 32, NEXP), 256, 0, stream>>>(
      a, w_out, y, b_out, meta, slot_token, CDIM, IDIM);
  combine_k<<<1024, 256, 0, stream>>>(y, topw, tok2slot, out);
}

// Round 7
// 197.908 us; speedup vs baseline: 1.3957x; 1.1070x over previous
//
#include <hip/hip_runtime.h>
#include <hip/hip_bf16.h>
#include <stdint.h>

#define TTOK 1024
#define CDIM 1024
#define NEXP 8
#define IDIM 1024
#define TWOI 2048
#define NSLOT 2048

typedef float f32x4 __attribute__((ext_vector_type(4)));
typedef short s16x8 __attribute__((ext_vector_type(8)));
typedef unsigned short u16;
typedef u16 u16x4 __attribute__((ext_vector_type(4)));
typedef u16 u16x8 __attribute__((ext_vector_type(8)));

__device__ __forceinline__ u16 f2bf(float f) {
  unsigned x = __float_as_uint(f);
  x += 0x7fffu + ((x >> 16) & 1u);
  return (u16)(x >> 16);
}

__device__ __forceinline__ void gload_lds16(const void* g, void* l) {
  __builtin_amdgcn_global_load_lds(
      (const __attribute__((address_space(1))) void*)g,
      (__attribute__((address_space(3))) void*)l, 16, 0, 0);
}

// ---------------- router: logits -> softmax -> top2; also emits bf16 x ----------------
__global__ __launch_bounds__(64) void router_k(const float* __restrict__ x,
                                               const float* __restrict__ rw,
                                               float* __restrict__ topw,
                                               int* __restrict__ topidx,
                                               u16* __restrict__ xb) {
  const int t = blockIdx.x;
  const int lane = threadIdx.x;
  float p[NEXP];
#pragma unroll
  for (int e = 0; e < NEXP; ++e) p[e] = 0.f;
  const float* xr = x + (size_t)t * CDIM;
  u16* xbr = xb + (size_t)t * CDIM;
  for (int c0 = lane * 4; c0 < CDIM; c0 += 64 * 4) {
    f32x4 xv = *(const f32x4*)(xr + c0);
    u16x4 xc;
#pragma unroll
    for (int q = 0; q < 4; ++q) xc[q] = f2bf(xv[q]);
    *(u16x4*)(xbr + c0) = xc;   // fused fp32->bf16 cast of x
#pragma unroll
    for (int e = 0; e < NEXP; ++e) {
      f32x4 wv = *(const f32x4*)(rw + (size_t)e * CDIM + c0);
      p[e] += xv[0] * wv[0] + xv[1] * wv[1] + xv[2] * wv[2] + xv[3] * wv[3];
    }
  }
#pragma unroll
  for (int e = 0; e < NEXP; ++e) {
    float v = p[e];
#pragma unroll
    for (int off = 32; off >= 1; off >>= 1) v += __shfl_xor(v, off);
    p[e] = v;
  }
  if (lane == 0) {
    float m = p[0];
#pragma unroll
    for (int e = 1; e < NEXP; ++e) m = fmaxf(m, p[e]);
    float pe[NEXP];
    float den = 0.f;
#pragma unroll
    for (int e = 0; e < NEXP; ++e) { pe[e] = __expf(p[e] - m); den += pe[e]; }
    int i0 = 0;
#pragma unroll
    for (int e = 1; e < NEXP; ++e) if (p[e] > p[i0]) i0 = e;
    int i1 = (i0 == 0) ? 1 : 0;
#pragma unroll
    for (int e = 0; e < NEXP; ++e) if (e != i0 && p[e] > p[i1]) i1 = e;
    const float inv = 1.f / den;
    topw[t * 2] = pe[i0] * inv;
    topw[t * 2 + 1] = pe[i1] * inv;
    topidx[t * 2] = i0;
    topidx[t * 2 + 1] = i1;
  }
}

// ---------------- build: histogram + prefix + scatter, one block ----------------
__global__ __launch_bounds__(1024) void build_k(const int* __restrict__ topidx,
                                                int* __restrict__ meta,
                                                int* __restrict__ slot_token,
                                                int* __restrict__ slot_expert,
                                                int* __restrict__ tok2slot) {
  __shared__ int cnt[NEXP], off[NEXP], cur[NEXP];
  const int t = threadIdx.x;
  if (t < NEXP) { cnt[t] = 0; cur[t] = 0; }
  __syncthreads();
  const int e0 = topidx[t * 2];
  const int e1 = topidx[t * 2 + 1];
  atomicAdd(&cnt[e0], 1);
  atomicAdd(&cnt[e1], 1);
  __syncthreads();
  if (t == 0) {
    int acc = 0;
    for (int e = 0; e < NEXP; ++e) { off[e] = acc; acc += cnt[e]; }
  }
  __syncthreads();
  if (t < NEXP) { meta[t] = cnt[t]; meta[16 + t] = off[t]; }
  {
    const int p0 = atomicAdd(&cur[e0], 1);
    const int s0 = off[e0] + p0;
    slot_token[s0] = t;
    slot_expert[s0] = e0;
    tok2slot[t * 2] = s0;
    const int p1 = atomicAdd(&cur[e1], 1);
    const int s1 = off[e1] + p1;
    slot_token[s1] = t;
    slot_expert[s1] = e1;
    tok2slot[t * 2 + 1] = s1;
  }
}

// ---------------- grouped GEMM, 2-phase pipelined (T3-minimum template) ----------------
// O[slot, n] = sum_k A[row(slot), k] * W[e, n, k]
// A bf16 [*, K]; W fp32 [E, N, K] (B^T layout); O fp32 [NSLOT, N]. BN = 64.
// Per K-step: issue next step's A gload_lds + B global loads FIRST, then
// ds_read+MFMA current, then cvt+ds_write next B, then ONE barrier.
template <int BM, bool GATHER, bool BIAS>
__global__ __launch_bounds__(256) void gemm_k(const u16* __restrict__ A,
                                              const float* __restrict__ W,
                                              float* __restrict__ O,
                                              const float* __restrict__ bias,
                                              const int* __restrict__ meta,
                                              const int* __restrict__ slot_token,
                                              int N, int K) {
  constexpr int BN = 64;
  constexpr int WM = BM / 2;
  constexpr int WN = BN / 2;
  constexpr int MR = WM / 16;
  constexpr int NR = WN / 16;
  constexpr int AG = BM / 32;   // A gload_lds per wave per step

  const int e = blockIdx.z;
  const int cnt = meta[e];
  const int m0 = blockIdx.y * BM;
  if (m0 >= cnt) return;
  const int off = meta[16 + e];
  const int n0 = blockIdx.x * BN;

  __shared__ u16 sA[2][BM * 64];
  __shared__ u16 sB[2][BN * 64];

  const int tid = threadIdx.x;
  const int lane = tid & 63;
  const int w = tid >> 6;
  const int wr = w >> 1;
  const int wc = w & 1;

  // A staging sources (pre-swizzled so LDS[r][c] holds global chunk c^(r&7)).
  const u16* aSrc[AG];
#pragma unroll
  for (int i = 0; i < AG; ++i) {
    const int r = w * (BM / 4) + i * 8 + (lane >> 3);
    int rr = m0 + r;
    if (rr > cnt - 1) rr = cnt - 1;  // clamp padded rows to a valid address
    const int rowg = GATHER ? slot_token[off + rr] : (off + rr);
    const int cs = (lane & 7) ^ (r & 7);
    aSrc[i] = A + (size_t)rowg * K + cs * 8;
  }
  // per-wave linear LDS offset for A (u16 elements)
  int aDst[AG];
#pragma unroll
  for (int i = 0; i < AG; ++i) aDst[i] = (w * (BM / 4) + i * 8) * 64 + lane * 8;

  // B staging: thread covers row tid>>2, quarter tid&3 (16 of 64 k); fp32->bf16.
  const int brow = tid >> 2;
  const int bq = tid & 3;
  const float* bSrc = W + ((size_t)e * N + (n0 + brow)) * K + bq * 16;
  const int brow7 = brow & 7;
  const int bOff0 = brow * 64 + (((bq * 2) ^ brow7) * 8);
  const int bOff1 = brow * 64 + (((bq * 2 + 1) ^ brow7) * 8);

  f32x4 acc[MR][NR];
#pragma unroll
  for (int m = 0; m < MR; ++m)
#pragma unroll
    for (int n = 0; n < NR; ++n) acc[m][n] = (f32x4){0.f, 0.f, 0.f, 0.f};

  // ---- prologue: stage step 0 into buffer 0 ----
  {
#pragma unroll
    for (int i = 0; i < AG; ++i) gload_lds16(aSrc[i], &sA[0][aDst[i]]);
    f32x4 v0 = *(const f32x4*)(bSrc);
    f32x4 v1 = *(const f32x4*)(bSrc + 4);
    f32x4 v2 = *(const f32x4*)(bSrc + 8);
    f32x4 v3 = *(const f32x4*)(bSrc + 12);
    u16x8 lo, hi;
#pragma unroll
    for (int q = 0; q < 4; ++q) lo[q] = f2bf(v0[q]);
#pragma unroll
    for (int q = 0; q < 4; ++q) lo[4 + q] = f2bf(v1[q]);
#pragma unroll
    for (int q = 0; q < 4; ++q) hi[q] = f2bf(v2[q]);
#pragma unroll
    for (int q = 0; q < 4; ++q) hi[4 + q] = f2bf(v3[q]);
    *(u16x8*)(&sB[0][bOff0]) = lo;
    *(u16x8*)(&sB[0][bOff1]) = hi;
  }
  __syncthreads();

  int c = 0;
  for (int k0 = 0; k0 < K; k0 += 64) {
    const int nk = k0 + 64;
    const bool has_next = nk < K;

    // 1) issue next step's loads FIRST (latency overlaps current compute)
    f32x4 v0, v1, v2, v3;
    if (has_next) {
#pragma unroll
      for (int i = 0; i < AG; ++i) gload_lds16(aSrc[i] + nk, &sA[1 - c][aDst[i]]);
      const float* bs = bSrc + nk;
      v0 = *(const f32x4*)(bs);
      v1 = *(const f32x4*)(bs + 4);
      v2 = *(const f32x4*)(bs + 8);
      v3 = *(const f32x4*)(bs + 12);
    }

    // 2) compute current step from buffer c
#pragma unroll
    for (int kh = 0; kh < 2; ++kh) {
      const int j = kh * 4 + (lane >> 4);
      s16x8 af[MR], bf[NR];
#pragma unroll
      for (int m = 0; m < MR; ++m) {
        const int r = wr * WM + m * 16 + (lane & 15);
        af[m] = *(const s16x8*)(&sA[c][r * 64 + ((j ^ (r & 7)) * 8)]);
      }
#pragma unroll
      for (int n = 0; n < NR; ++n) {
        const int r = wc * WN + n * 16 + (lane & 15);
        bf[n] = *(const s16x8*)(&sB[c][r * 64 + ((j ^ (r & 7)) * 8)]);
      }
#pragma unroll
      for (int m = 0; m < MR; ++m)
#pragma unroll
        for (int n = 0; n < NR; ++n)
          acc[m][n] = __builtin_amdgcn_mfma_f32_16x16x32_bf16(af[m], bf[n], acc[m][n], 0, 0, 0);
    }

    // 3) convert + write next B into buffer 1-c (compiler waits vmcnt here)
    if (has_next) {
      u16x8 lo, hi;
#pragma unroll
      for (int q = 0; q < 4; ++q) lo[q] = f2bf(v0[q]);
#pragma unroll
      for (int q = 0; q < 4; ++q) lo[4 + q] = f2bf(v1[q]);
#pragma unroll
      for (int q = 0; q < 4; ++q) hi[q] = f2bf(v2[q]);
#pragma unroll
      for (int q = 0; q < 4; ++q) hi[4 + q] = f2bf(v3[q]);
      *(u16x8*)(&sB[1 - c][bOff0]) = lo;
      *(u16x8*)(&sB[1 - c][bOff1]) = hi;
    }

    // 4) single barrier per step (drains gload_lds vmcnt + ds_write lgkm)
    __syncthreads();
    c ^= 1;
  }

  // epilogue: C/D layout col=lane&15, row=(lane>>4)*4+reg
#pragma unroll
  for (int m = 0; m < MR; ++m) {
#pragma unroll
    for (int jj = 0; jj < 4; ++jj) {
      const int tr = wr * WM + m * 16 + ((lane >> 4) * 4) + jj;
      if (m0 + tr < cnt) {
        const size_t slot = (size_t)(off + m0 + tr);
#pragma unroll
        for (int n = 0; n < NR; ++n) {
          const int col = n0 + wc * WN + n * 16 + (lane & 15);
          float v = acc[m][n][jj];
          if (BIAS) v += bias[(size_t)e * N + col];
          O[slot * N + col] = v;
        }
      }
    }
  }
}

// ---------------- swiglu: a = silu(g + bg) * (u + bu), bf16 ----------------
__global__ __launch_bounds__(256) void swiglu_k(const float* __restrict__ h,
                                                const float* __restrict__ b_in,
                                                const int* __restrict__ slot_expert,
                                                u16* __restrict__ a) {
  const int s = blockIdx.x;
  const int e = slot_expert[s];
  const int i = threadIdx.x * 4;
  f32x4 g = *(const f32x4*)(h + (size_t)s * TWOI + i);
  f32x4 u = *(const f32x4*)(h + (size_t)s * TWOI + IDIM + i);
  f32x4 bg = *(const f32x4*)(b_in + (size_t)e * TWOI + i);
  f32x4 bu = *(const f32x4*)(b_in + (size_t)e * TWOI + IDIM + i);
  u16x4 o;
#pragma unroll
  for (int q = 0; q < 4; ++q) {
    const float gg = g[q] + bg[q];
    const float uu = u[q] + bu[q];
    const float sv = gg / (1.f + __expf(-gg));
    o[q] = f2bf(sv * uu);
  }
  *(u16x4*)(a + (size_t)s * IDIM + i) = o;
}

// ---------------- combine: out[t] = w0*y[s0] + w1*y[s1] ----------------
__global__ __launch_bounds__(256) void combine_k(const float* __restrict__ y,
                                                 const float* __restrict__ topw,
                                                 const int* __restrict__ tok2slot,
                                                 float* __restrict__ out) {
  const int idx = blockIdx.x * 256 + threadIdx.x;  // over T*C/4
  const int t = idx >> 8;
  const int c4 = (idx & 255) * 4;
  const int s0 = tok2slot[t * 2];
  const int s1 = tok2slot[t * 2 + 1];
  const float w0 = topw[t * 2];
  const float w1 = topw[t * 2 + 1];
  f32x4 y0 = *(const f32x4*)(y + (size_t)s0 * CDIM + c4);
  f32x4 y1 = *(const f32x4*)(y + (size_t)s1 * CDIM + c4);
  f32x4 o;
#pragma unroll
  for (int q = 0; q < 4; ++q) o[q] = w0 * y0[q] + w1 * y1[q];
  *(f32x4*)(out + (size_t)t * CDIM + c4) = o;
}

extern "C" void kernel_launch(void* const* d_in, const int* in_sizes, int n_in,
                              void* d_out, int out_size, void* d_ws, size_t ws_size,
                              hipStream_t stream) {
  const float* x = (const float*)d_in[0];
  const float* rw = (const float*)d_in[1];
  const float* w_in = (const float*)d_in[2];
  const float* b_in = (const float*)d_in[3];
  const float* w_out = (const float*)d_in[4];
  const float* b_out = (const float*)d_in[5];
  float* out = (float*)d_out;
  char* ws = (char*)d_ws;

  // ws layout (bytes)
  int* meta = (int*)ws;                               // counts@0, offsets@16
  int* slot_token = (int*)(ws + 1024);                // 2048 ints
  int* slot_expert = (int*)(ws + 1024 + 8192);        // 2048 ints
  int* tok2slot = (int*)(ws + 1024 + 16384);          // 2048 ints
  float* topw = (float*)(ws + 1024 + 24576);          // 2048 f32
  int* topidx = (int*)(ws + 1024 + 32768);            // 2048 ints
  u16* xb = (u16*)(ws + 65536);                       // 1M bf16 = 2MB
  float* h = (float*)(ws + 65536 + (2u << 20));       // 2048*2048 f32 = 16MB
  u16* a = (u16*)(ws + 65536 + (18u << 20));          // 2048*1024 bf16 = 4MB
  float* y = (float*)(ws + 65536 + (22u << 20));      // 2048*1024 f32 = 8MB

  // no memset needed: build_k rewrites every meta field read downstream.
  router_k<<<TTOK, 64, 0, stream>>>(x, rw, topw, topidx, xb);
  build_k<<<1, 1024, 0, stream>>>(topidx, meta, slot_token, slot_expert, tok2slot);
  // GEMM1: BM=128, BN=64 -> 32 n-tiles; ~512 active blocks (2/CU) at cnt~256.
  gemm_k<128, true, false><<<dim3(32, 16, NEXP), 256, 0, stream>>>(
      xb, w_in, h, nullptr, meta, slot_token, TWOI, CDIM);
  swiglu_k<<<NSLOT, 256, 0, stream>>>(h, b_in, slot_expert, a);
  // GEMM2: BM=64, BN=64 -> 16 n-tiles; ~512 active blocks (2/CU) at cnt~256.
  gemm_k<64, false, true><<<dim3(16, 32, NEXP), 256, 0, stream>>>(
      a, w_out, y, b_out, meta, slot_token, CDIM, IDIM);
  combine_k<<<1024, 256, 0, stream>>>(y, topw, tok2slot, out);
}